// Round 1
// 1098.359 us; speedup vs baseline: 1.0210x; 1.0210x over previous
//
#include <hip/hip_runtime.h>
#include <math.h>

// FNO-3D spectral convolution via separable partial DFTs (no full FFT).
// x: (16,192,192,192) f32; wr/wi: (4,16,16,16,16,16) f32; out: (16,192,192,192) f32.
//  k0a: build T1 twiddle table (24 KB) in Xf slot (dead until K3)
//  K1: z-DFT  (192 -> 16 modes, real input)   A[c][x][y][kz]      75.5 MB
//      lane=row, x-chunk in regs, twiddles via wave-uniform s_load
//  K2: y-DFT  (192 -> 32 modes)               B[c][x][ky][kz]     12.6 MB
//  K3: x-DFT  (192 -> 32 modes)               Xf[c][kx][ky][kz]    2.1 MB (clobbers T1)
//  K4: channel mix + fold (eps_kz / N^3)      Y[o][kx][ky][kz]     2.1 MB  (o-split grid, 4096 waves)
//  K5: inverse x-expand (32 -> 192)           G1 (reuses B slot)
//  k0b: build T32 table (48 KB) in Y slot (Y dead after K5)
//  K6: inverse y-expand (32 -> 192)           G2 (reuses A slot)
//      lane=(x,kz) row, G1 in regs, scalar twiddles
//  K7: inverse z-expand + Re(.)  -> out (453 MB)
//      lane=z, twiddles in regs, G-row via wave-uniform s_load, NO LDS
// ws peak = 92.3 MB (tables aliased into dead phases).

#define NN 192
#define NC 16
#define NM 16
#define NK2 32

constexpr float TWOPI  = 6.283185307179586476925286766559f;
constexpr float INV_N3 = 1.0f / (192.0f * 192.0f * 192.0f);

__device__ __forceinline__ void fill_T(float2* T) {
  int t = threadIdx.x;
  if (t < NN) {
    float s, c;
    sincosf((TWOPI / NN) * (float)t, &s, &c);
    T[t] = make_float2(c, s);   // (cos, +sin); signs handled per stage
  }
}

// ---------------- k0a: forward z twiddle table T1[z][kz] = (cos, -sin) ----------------
__global__ __launch_bounds__(256) void k0a_t1(float2* __restrict__ T1) {
  int idx = blockIdx.x * 256 + threadIdx.x;      // 12 blocks -> 3072
  int z = idx >> 4, kz = idx & 15;
  float s, c;
  sincosf((TWOPI / NN) * (float)((z * kz) % NN), &s, &c);
  T1[idx] = make_float2(c, -s);
}

// ---------------- k0b: inverse twiddle table T32[f][j] = (cos, +sin) ----------------
// j<16 -> freq j ; j>=16 -> freq 160+j (= 176+(j-16))
__global__ __launch_bounds__(256) void k0b_t32(float2* __restrict__ T32) {
  int idx = blockIdx.x * 256 + threadIdx.x;      // 24 blocks -> 6144
  int f = idx >> 5, j = idx & 31;
  int freq = (j < 16) ? j : (160 + j);
  float s, c;
  sincosf((TWOPI / NN) * (float)((f * freq) % NN), &s, &c);
  T32[idx] = make_float2(c, s);
}

// ---------------- K1: forward z-DFT (real -> 16 complex modes) ----------------
// lane = row (c,x,y); 16-z register chunks; twiddles wave-uniform (s_load path).
__global__ __launch_bounds__(256) void k1_fwd_z(const float* __restrict__ x,
                                                const float2* __restrict__ T1,
                                                float2* __restrict__ A) {
  const int r = blockIdx.x * 256 + threadIdx.x;   // 2304 blocks -> 589824 rows
  const float* __restrict__ xr = x + (size_t)r * NN;
  float ar[NM], ai[NM];
#pragma unroll
  for (int k = 0; k < NM; ++k) { ar[k] = 0.f; ai[k] = 0.f; }
#pragma unroll 1
  for (int zc = 0; zc < 12; ++zc) {
    float4 v[4];
    const float4* src = (const float4*)(xr + zc * 16);
#pragma unroll
    for (int q = 0; q < 4; ++q) v[q] = src[q];
#pragma unroll
    for (int zz = 0; zz < 16; ++zz) {
      const float xv = ((const float*)v)[zz];          // compile-time index
      const float2* tz = T1 + (zc * 16 + zz) * NM;     // wave-uniform
#pragma unroll
      for (int kz = 0; kz < NM; ++kz) {
        float2 w = tz[kz];
        ar[kz] = fmaf(xv, w.x, ar[kz]);
        ai[kz] = fmaf(xv, w.y, ai[kz]);   // w.y = -sin
      }
    }
  }
  float4* dst = (float4*)(A + (size_t)r * NM);
#pragma unroll
  for (int h = 0; h < 8; ++h)
    dst[h] = make_float4(ar[2 * h], ai[2 * h], ar[2 * h + 1], ai[2 * h + 1]);
}

// ---------------- K2: forward y-DFT (192 -> 32 modes), complex ----------------
__global__ __launch_bounds__(256) void k2_fwd_y(const float2* __restrict__ A,
                                                float2* __restrict__ B) {
  __shared__ __align__(16) float2 As[NN * NM];   // 24 KB
  __shared__ float2 T[NN];
  const int t = threadIdx.x;
  fill_T(T);
  const int cx = blockIdx.x;                     // c*192 + x
  const float4* src = (const float4*)(A + (size_t)cx * NN * NM);
  float4* dl = (float4*)As;
#pragma unroll
  for (int k = 0; k < 6; ++k) dl[t + k * 256] = src[t + k * 256];
  __syncthreads();
  const int kz = t & 15;
  const int kyq = t >> 4;            // handles ky = kyq and ky = 16+kyq (f = 176+kyq)
  const int s1 = 176 + kyq;
  float2 a0 = make_float2(0.f, 0.f), a1 = make_float2(0.f, 0.f);
  int p0 = 0, p1 = 0;
#pragma unroll 4
  for (int y = 0; y < NN; ++y) {
    float2 a = As[y * NM + kz];
    float2 w0 = T[p0]; p0 += kyq; p0 = (p0 >= NN) ? p0 - NN : p0;
    float2 w1 = T[p1]; p1 += s1;  p1 = (p1 >= NN) ? p1 - NN : p1;
    a0.x = fmaf(a.x, w0.x, fmaf(a.y, w0.y, a0.x));
    a0.y = fmaf(a.y, w0.x, fmaf(-a.x, w0.y, a0.y));
    a1.x = fmaf(a.x, w1.x, fmaf(a.y, w1.y, a1.x));
    a1.y = fmaf(a.y, w1.x, fmaf(-a.x, w1.y, a1.y));
  }
  float2* dst = B + (size_t)cx * NK2 * NM;
  dst[kyq * NM + kz] = a0;
  dst[(16 + kyq) * NM + kz] = a1;
}

// ---------------- K3: forward x-DFT (192 -> 32 modes), complex ----------------
__global__ __launch_bounds__(256) void k3_fwd_x(const float2* __restrict__ B,
                                                float2* __restrict__ Xf) {
  __shared__ __align__(16) float2 Bs[NN * NM];
  __shared__ float2 T[NN];
  const int t = threadIdx.x;
  fill_T(T);
  const int c = blockIdx.x >> 5, ky = blockIdx.x & 31;
#pragma unroll
  for (int k = 0; k < 6; ++k) {
    int i = t + k * 256;            // float4 index < 1536; i = xx*8 + q
    int xx = i >> 3, q = i & 7;
    ((float4*)Bs)[i] = *((const float4*)(B + ((size_t)(c * NN + xx) * NK2 + ky) * NM) + q);
  }
  __syncthreads();
  const int kz = t & 15, kxq = t >> 4;
  const int s1 = 176 + kxq;
  float2 a0 = make_float2(0.f, 0.f), a1 = make_float2(0.f, 0.f);
  int p0 = 0, p1 = 0;
#pragma unroll 4
  for (int xx = 0; xx < NN; ++xx) {
    float2 b = Bs[xx * NM + kz];
    float2 w0 = T[p0]; p0 += kxq; p0 = (p0 >= NN) ? p0 - NN : p0;
    float2 w1 = T[p1]; p1 += s1;  p1 = (p1 >= NN) ? p1 - NN : p1;
    a0.x = fmaf(b.x, w0.x, fmaf(b.y, w0.y, a0.x));
    a0.y = fmaf(b.y, w0.x, fmaf(-b.x, w0.y, a0.y));
    a1.x = fmaf(b.x, w1.x, fmaf(b.y, w1.y, a1.x));
    a1.y = fmaf(b.y, w1.x, fmaf(-b.x, w1.y, a1.y));
  }
  Xf[((size_t)(c * NK2 + kxq) * NK2 + ky) * NM + kz] = a0;
  Xf[((size_t)(c * NK2 + 16 + kxq) * NK2 + ky) * NM + kz] = a1;
}

// ---------------- K4: channel mix + scale fold (o-split grid) ----------------
// grid = 64 mode-chunks x 16 o; each w element still read exactly once.
__global__ __launch_bounds__(256) void k4_mix(const float2* __restrict__ Xf,
                                              const float* __restrict__ wr,
                                              const float* __restrict__ wi,
                                              float2* __restrict__ Y) {
  const int o  = blockIdx.x & 15;
  const int mc = blockIdx.x >> 4;
  const int tm = mc * 256 + threadIdx.x;
  const int kz = tm & 15, ky = (tm >> 4) & 31, kx = tm >> 9;
  const int q = (kx >= 16 ? 1 : 0) + (ky >= 16 ? 2 : 0);
  const int modeW = ((kx & 15) * 16 + (ky & 15)) * 16 + kz;
  float cr = 0.f, ci = 0.f;
#pragma unroll
  for (int i = 0; i < NC; ++i) {
    float2 v = Xf[i * 16384 + tm];
    size_t wIdx = (size_t)((q * 16 + i) * 16 + o) * 4096 + modeW;
    float a = wr[wIdx], b = wi[wIdx];
    cr = fmaf(v.x, a, fmaf(-v.y, b, cr));
    ci = fmaf(v.x, b, fmaf(v.y, a, ci));
  }
  const float scale = (kz == 0 ? 1.0f : 2.0f) * INV_N3;
  Y[o * 16384 + tm] = make_float2(cr * scale, ci * scale);
}

// ---------------- K5: inverse x-expand (32 modes -> 192) ----------------
__global__ __launch_bounds__(256) void k5_inv_x(const float2* __restrict__ Y,
                                                float2* __restrict__ G1) {
  __shared__ __align__(16) float2 Ys[NK2 * NM];
  __shared__ float2 T[NN];
  const int t = threadIdx.x;
  fill_T(T);
  const int c = blockIdx.x >> 5, ky = blockIdx.x & 31;
  {
    int kx = t >> 3, qq = t & 7;
    ((float4*)Ys)[t] = *((const float4*)(Y + (size_t)c * 16384 + (size_t)kx * (NK2 * NM) + ky * NM) + qq);
  }
  __syncthreads();
  const int kz = t & 15, xq = t >> 4;
#pragma unroll 1
  for (int j = 0; j < 12; ++j) {
    const int xx = xq + 16 * j;
    float2 acc = make_float2(0.f, 0.f);
    const int step = xx;
    int p = 0;                       // f=kx half: p = kx*xx mod 192
#pragma unroll
    for (int k = 0; k < 16; ++k) {
      float2 v = Ys[k * NM + kz];
      float2 w = T[p]; p += step; p = (p >= NN) ? p - NN : p;
      acc.x = fmaf(v.x, w.x, fmaf(-v.y, w.y, acc.x));
      acc.y = fmaf(v.y, w.x, fmaf( v.x, w.y, acc.y));
    }
    int p2 = (176 * xx) % NN;        // f=176+k half
#pragma unroll
    for (int k = 0; k < 16; ++k) {
      float2 v = Ys[(16 + k) * NM + kz];
      float2 w = T[p2]; p2 += step; p2 = (p2 >= NN) ? p2 - NN : p2;
      acc.x = fmaf(v.x, w.x, fmaf(-v.y, w.y, acc.x));
      acc.y = fmaf(v.y, w.x, fmaf( v.x, w.y, acc.y));
    }
    G1[((size_t)(c * NN + xx) * NK2 + ky) * NM + kz] = acc;
  }
}

// ---------------- K6: inverse y-expand (32 modes -> 192) ----------------
// lane = (xi,kz); G1 row (32 complex) in regs; twiddles wave-uniform s_load.
// grid = (16c * 12 xg) * 4 y-splits = 768 blocks.
__global__ __launch_bounds__(256) void k6_inv_y(const float2* __restrict__ G1,
                                                const float2* __restrict__ T32,
                                                float2* __restrict__ G2) {
  const int t = threadIdx.x;
  const int kz = t & 15, xi = t >> 4;
  const int ys = blockIdx.x & 3;
  const int g  = blockIdx.x >> 2;            // 0..191 = c*12 + xg
  const int c  = g / 12, xg = g - c * 12;
  const int x  = xg * 16 + xi;
  const size_t cx = (size_t)(c * NN + x);
  float gr[NK2], gi[NK2];
  const float2* __restrict__ src = G1 + cx * NK2 * NM + kz;
#pragma unroll
  for (int k = 0; k < NK2; ++k) {
    float2 v = src[k * NM];
    gr[k] = v.x; gi[k] = v.y;
  }
  float2* dst = G2 + cx * NN * NM + kz;
  const int y0 = ys * 48;
#pragma unroll 1
  for (int y = y0; y < y0 + 48; ++y) {
    const float2* tw = T32 + y * NK2;        // wave-uniform
    float sr = 0.f, si = 0.f;
#pragma unroll
    for (int k = 0; k < NK2; ++k) {
      float2 w = tw[k];
      sr = fmaf(gr[k], w.x, fmaf(-gi[k], w.y, sr));
      si = fmaf(gi[k], w.x, fmaf( gr[k], w.y, si));
    }
    dst[y * NM] = make_float2(sr, si);
  }
}

// ---------------- K7: inverse z-expand, real output (NO LDS) ----------------
// lane = z; twiddles (16 pairs) in regs from T32; G row via wave-uniform loads.
__global__ __launch_bounds__(192) void k7_inv_z(const float2* __restrict__ G2,
                                                const float2* __restrict__ T32,
                                                float* __restrict__ out) {
  const int z = threadIdx.x;                   // 0..191
  const int cx = blockIdx.x;                   // 3072
  float twc[16], tws[16];
  const float4* tz = (const float4*)(T32 + (size_t)z * NK2);  // first 16 pairs
#pragma unroll
  for (int h = 0; h < 8; ++h) {
    float4 w = tz[h];
    twc[2 * h]     = w.x; tws[2 * h]     = w.y;
    twc[2 * h + 1] = w.z; tws[2 * h + 1] = w.w;
  }
  const float2* __restrict__ gbase = G2 + (size_t)cx * NN * NM;
  float* obase = out + (size_t)cx * NN * NN;
#pragma unroll 2
  for (int y = 0; y < NN; ++y) {
    const float2* gy = gbase + y * NM;         // wave-uniform address
    float acc = 0.f;
#pragma unroll
    for (int kz = 0; kz < NM; ++kz) {
      float2 v = gy[kz];
      acc = fmaf(v.x, twc[kz], fmaf(-v.y, tws[kz], acc));
    }
    obase[y * NN + z] = acc;
  }
}

extern "C" void kernel_launch(void* const* d_in, const int* in_sizes, int n_in,
                              void* d_out, int out_size, void* d_ws, size_t ws_size,
                              hipStream_t stream) {
  const float* x  = (const float*)d_in[0];
  const float* wr = (const float*)d_in[1];
  const float* wi = (const float*)d_in[2];
  float* out = (float*)d_out;

  // workspace layout (float2 units); G1 reuses B, G2 reuses A. Peak 92.3 MB.
  // T1 (3072 fl2) aliases Xf (dead until K3 writes it).
  // T32 (6144 fl2) aliases Y (dead after K5 reads it).
  float2* A  = (float2*)d_ws;          // 9437184 fl2
  float2* B  = A  + 9437184;           // 1572864 fl2
  float2* Xf = B  + 1572864;           //  262144 fl2
  float2* Y  = Xf + 262144;            //  262144 fl2
  float2* G1 = B;
  float2* G2 = A;
  float2* T1  = Xf;
  float2* T32 = Y;

  k0a_t1 <<<dim3(12),   dim3(256), 0, stream>>>(T1);
  k1_fwd_z<<<dim3(2304), dim3(256), 0, stream>>>(x, T1, A);
  k2_fwd_y<<<dim3(3072), dim3(256), 0, stream>>>(A, B);
  k3_fwd_x<<<dim3(512),  dim3(256), 0, stream>>>(B, Xf);   // clobbers T1 (dead)
  k4_mix  <<<dim3(1024), dim3(256), 0, stream>>>(Xf, wr, wi, Y);
  k5_inv_x<<<dim3(512),  dim3(256), 0, stream>>>(Y, G1);
  k0b_t32<<<dim3(24),   dim3(256), 0, stream>>>(T32);      // Y dead after K5
  k6_inv_y<<<dim3(768),  dim3(256), 0, stream>>>(G1, T32, G2);
  k7_inv_z<<<dim3(3072), dim3(192), 0, stream>>>(G2, T32, out);
}